// Round 5
// baseline (489.652 us; speedup 1.0000x reference)
//
#include <hip/hip_runtime.h>

typedef __bf16 bf16;
typedef __bf16 bf16x4 __attribute__((ext_vector_type(4)));
typedef __bf16 bf16x8 __attribute__((ext_vector_type(8)));
typedef float f32x4 __attribute__((ext_vector_type(4)));

#define GLP16(gp, lp) __builtin_amdgcn_global_load_lds( \
    (const __attribute__((address_space(1))) void*)(gp), \
    (__attribute__((address_space(3))) void*)(lp), 16, 0, 0)

__device__ __forceinline__ f32x4 mfma16(bf16x8 a, bf16x8 b, f32x4 c) {
    return __builtin_amdgcn_mfma_f32_16x16x32_bf16(a, b, c, 0, 0, 0);
}

// ---------------- RMSNorm: fp32 in -> bf16 out, row = 2048 ----------------
__global__ __launch_bounds__(256) void k_rmsnorm(const float* __restrict__ x,
        const float* __restrict__ w, bf16* __restrict__ out) {
    const int H = 2048;
    size_t row = blockIdx.x;
    const float* xr = x + row * H;
    int base = threadIdx.x * 8;
    float4 a = *(const float4*)(xr + base);
    float4 b = *(const float4*)(xr + base + 4);
    float ss = a.x*a.x + a.y*a.y + a.z*a.z + a.w*a.w
             + b.x*b.x + b.y*b.y + b.z*b.z + b.w*b.w;
#pragma unroll
    for (int m = 32; m > 0; m >>= 1) ss += __shfl_xor(ss, m);
    __shared__ float red[4];
    if ((threadIdx.x & 63) == 0) red[threadIdx.x >> 6] = ss;
    __syncthreads();
    float tot = red[0] + red[1] + red[2] + red[3];
    float rs = rsqrtf(tot * (1.0f / H) + 1e-5f);
    float4 wa = *(const float4*)(w + base);
    float4 wb = *(const float4*)(w + base + 4);
    bf16x8 ov;
    ov[0] = (bf16)(a.x * rs * wa.x); ov[1] = (bf16)(a.y * rs * wa.y);
    ov[2] = (bf16)(a.z * rs * wa.z); ov[3] = (bf16)(a.w * rs * wa.w);
    ov[4] = (bf16)(b.x * rs * wb.x); ov[5] = (bf16)(b.y * rs * wb.y);
    ov[6] = (bf16)(b.z * rs * wb.z); ov[7] = (bf16)(b.w * rs * wb.w);
    *(bf16x8*)(out + row * H + base) = ov;
}

// ------- convert + transpose: W (K x N fp32) -> Wt (N x K bf16) -----------
__global__ __launch_bounds__(256) void k_convT(const float* __restrict__ W,
        bf16* __restrict__ Wt, int K, int N) {
    __shared__ float t[32][33];
    int k0 = blockIdx.x * 32, n0 = blockIdx.y * 32;
    int tx = threadIdx.x, ty = threadIdx.y;
#pragma unroll
    for (int i = 0; i < 4; i++)
        t[ty + i * 8][tx] = W[(size_t)(k0 + ty + i * 8) * N + n0 + tx];
    __syncthreads();
#pragma unroll
    for (int i = 0; i < 4; i++)
        Wt[(size_t)(n0 + ty + i * 8) * K + k0 + tx] = (bf16)t[tx][ty + i * 8];
}

// ------- bf16 transpose: in (R x C) -> out (C x R) ------------------------
__global__ __launch_bounds__(256) void k_transpose(const bf16* __restrict__ in,
        bf16* __restrict__ out, int R, int C) {
    __shared__ bf16 t[32][33];
    int r0 = blockIdx.x * 32, c0 = blockIdx.y * 32;
    int tx = threadIdx.x & 31, ty = threadIdx.x >> 5;
#pragma unroll
    for (int i = 0; i < 4; i++)
        t[ty + i * 8][tx] = in[(size_t)(r0 + ty + i * 8) * C + c0 + tx];
    __syncthreads();
#pragma unroll
    for (int i = 0; i < 4; i++)
        out[(size_t)(c0 + ty + i * 8) * R + r0 + tx] = t[tx][ty + i * 8];
}

// ---------------- GEMM v3: 256x256 tile, 8-phase-style schedule -----------
// BM=BN=256, K-steps of 32. 8 waves (2M x 4N), per-wave 128x64 output.
// LDS 128KB: A-slabs 4 x 16KB @0; B-slabs 4 x 16KB @64KB (circular, idx s&3).
// Slab layout: 2 rows packed per 128B line, XOR-swizzled byte^=((line&7)<<4);
// GLP dest linear, global source pre-swizzled (rule 21). 2-way conflicts only.
// Per step: phase A {ds_read A[m0-3]+B[n0-3] (8), issue A-slab(s+3), barrier,
// lgkmcnt(0), setprio, 16 MFMA, setprio, barrier}; phase B {ds_read A[m4-7]
// (4), issue B-slab(s+3), ..., 16 MFMA}; boundary vmcnt(8) -- never 0.
// Slab s+3 overwrites slab (s-1)&3 whose readers all passed the end-of-step
// s-1 barrier => race-free.
// EPI: 0 = bf16 store, 2 = silu(aux)*acc -> bf16, 3 = fp32 partial (split-K)
template<int EPI>
__global__ __launch_bounds__(512, 2) void k_gemm3(const bf16* __restrict__ A,
        const bf16* __restrict__ Bt, void* __restrict__ outp,
        const void* __restrict__ aux, int M, int N, int K, int ksplit) {
    extern __shared__ char lds[];
    const int tid = threadIdx.x, wave = tid >> 6, lane = tid & 63;
    const int lr = lane & 15, kg = lane >> 4;
    const int wm = wave >> 2, wn = wave & 3;
    const int bn = blockIdx.x, bm = blockIdx.y, split = blockIdx.z;
    const int row0 = bm * 256, col0 = bn * 256;
    const int kbeg = split * ksplit;
    const int NT = ksplit >> 5;
    const size_t K2 = (size_t)K * 2;

    // staging: linear dest byte d (16KB slab) -> global source byte offset
    size_t offS[2];
#pragma unroll
    for (int s = 0; s < 2; s++) {
        int d = s * 8192 + tid * 16;
        int line = d >> 7, w = d & 127;
        int w2 = w ^ ((line & 7) << 4);
        offS[s] = (size_t)(line * 2 + (w2 >> 6)) * K2 + (w2 & 63);
    }
    const char* Ab = (const char*)A + ((size_t)row0 * K + kbeg) * 2;
    const char* Bb = (const char*)Bt + ((size_t)col0 * K + kbeg) * 2;

    auto stA = [&](int s) {
        const char* src = Ab + (size_t)s * 64;
        char* dst = lds + (s & 3) * 16384 + wave * 1024;
        GLP16(src + offS[0], dst);
        GLP16(src + offS[1], dst + 8192);
    };
    auto stB = [&](int s) {
        const char* src = Bb + (size_t)s * 64;
        char* dst = lds + 65536 + (s & 3) * 16384 + wave * 1024;
        GLP16(src + offS[0], dst);
        GLP16(src + offS[1], dst + 8192);
    };
    // fragment read: slab base + row (0..255) -> 16B at swizzled position
    auto frag = [&](const char* base, int row) -> bf16x8 {
        int line = row >> 1;
        int pos = (((row & 1) << 6) + (kg << 4)) ^ ((line & 7) << 4);
        return *(const bf16x8*)(base + line * 128 + pos);
    };

    f32x4 acc[8][4];
#pragma unroll
    for (int m = 0; m < 8; m++)
#pragma unroll
        for (int n = 0; n < 4; n++) acc[m][n] = (f32x4){0, 0, 0, 0};

    // prologue: stage steps 0,1,2 (A+B each); wait step 0 (leave 8 in flight)
    stA(0); stB(0);
    if (NT > 1) { stA(1); stB(1); }
    if (NT > 2) { stA(2); stB(2); }
    if (NT > 2)      asm volatile("s_waitcnt vmcnt(8)" ::: "memory");
    else if (NT > 1) asm volatile("s_waitcnt vmcnt(4)" ::: "memory");
    else             asm volatile("s_waitcnt vmcnt(0)" ::: "memory");
    __builtin_amdgcn_s_barrier();

    for (int s = 0; s < NT; ++s) {
        const char* As_ = lds + (s & 3) * 16384;
        const char* Bs_ = lds + 65536 + (s & 3) * 16384;
        // ---- phase A: A-frags m0-3, all B-frags; stage A(s+3)
        bf16x8 av[4], bv[4];
#pragma unroll
        for (int m = 0; m < 4; m++) av[m] = frag(As_, wm * 128 + m * 16 + lr);
#pragma unroll
        for (int n = 0; n < 4; n++) bv[n] = frag(Bs_, wn * 64 + n * 16 + lr);
        if (s + 3 < NT) stA(s + 3);
        __builtin_amdgcn_s_barrier();
        asm volatile("s_waitcnt lgkmcnt(0)" ::: "memory");
        __builtin_amdgcn_s_setprio(1);
#pragma unroll
        for (int m = 0; m < 4; m++)
#pragma unroll
            for (int n = 0; n < 4; n++)
                acc[m][n] = mfma16(av[m], bv[n], acc[m][n]);
        __builtin_amdgcn_s_setprio(0);
        __builtin_amdgcn_s_barrier();
        // ---- phase B: A-frags m4-7 (B reused from regs); stage B(s+3)
        bf16x8 aw[4];
#pragma unroll
        for (int m = 0; m < 4; m++) aw[m] = frag(As_, wm * 128 + (m + 4) * 16 + lr);
        if (s + 3 < NT) stB(s + 3);
        __builtin_amdgcn_s_barrier();
        asm volatile("s_waitcnt lgkmcnt(0)" ::: "memory");
        __builtin_amdgcn_s_setprio(1);
#pragma unroll
        for (int m = 0; m < 4; m++)
#pragma unroll
            for (int n = 0; n < 4; n++)
                acc[m + 4][n] = mfma16(aw[m], bv[n], acc[m + 4][n]);
        __builtin_amdgcn_s_setprio(0);
        // ---- boundary: step s+1 must have arrived; keep s+2,s+3 in flight
        if (s + 3 < NT)      asm volatile("s_waitcnt vmcnt(8)" ::: "memory");
        else if (s + 2 < NT) asm volatile("s_waitcnt vmcnt(4)" ::: "memory");
        else if (s + 1 < NT) asm volatile("s_waitcnt vmcnt(0)" ::: "memory");
        __builtin_amdgcn_s_barrier();
    }

#pragma unroll
    for (int m = 0; m < 8; m++)
#pragma unroll
        for (int n = 0; n < 4; n++)
#pragma unroll
            for (int r = 0; r < 4; r++) {
                size_t row = row0 + wm * 128 + m * 16 + kg * 4 + r;
                size_t col = col0 + wn * 64 + n * 16 + lr;
                size_t idx = row * N + col;
                float vv = acc[m][n][r];
                if (EPI == 0) {
                    ((bf16*)outp)[idx] = (bf16)vv;
                } else if (EPI == 2) {
                    float g = (float)((const bf16*)aux)[idx];
                    float sg = g / (1.0f + __expf(-g));
                    ((bf16*)outp)[idx] = (bf16)(sg * vv);
                } else {
                    ((float*)outp)[(size_t)split * M * N + idx] = vv;
                }
            }
}

// ---- reduce: out = resid + sum_s parts[s], fp32, vectorized float4 -------
__global__ __launch_bounds__(256) void k_reduce(const float* __restrict__ parts,
        const float* __restrict__ resid, float* __restrict__ out,
        int ns, size_t n4) {
    size_t i = (size_t)blockIdx.x * 256 + threadIdx.x;
    if (i >= n4) return;
    float4 acc = ((const float4*)resid)[i];
    for (int s = 0; s < ns; s++) {
        float4 p = ((const float4*)(parts + (size_t)s * n4 * 4))[i];
        acc.x += p.x; acc.y += p.y; acc.z += p.z; acc.w += p.w;
    }
    ((float4*)out)[i] = acc;
}

// ---- fused: x2 = resid + sum parts; hb = rmsnorm(x2)*w  (row = 2048) -----
__global__ __launch_bounds__(256) void k_reduce_rms(const float* __restrict__ parts,
        const float* __restrict__ resid, const float* __restrict__ w,
        float* __restrict__ x2, bf16* __restrict__ hb, int ns) {
    const int H = 2048;
    size_t row = blockIdx.x;
    int base = threadIdx.x * 8;
    const float* rr = resid + row * H + base;
    float4 a = *(const float4*)rr;
    float4 b = *(const float4*)(rr + 4);
    for (int s = 0; s < ns; s++) {
        const float* pp = parts + (size_t)s * H * 2048 + row * H + base;
        float4 pa = *(const float4*)pp;
        float4 pb = *(const float4*)(pp + 4);
        a.x += pa.x; a.y += pa.y; a.z += pa.z; a.w += pa.w;
        b.x += pb.x; b.y += pb.y; b.z += pb.z; b.w += pb.w;
    }
    *(float4*)(x2 + row * H + base) = a;
    *(float4*)(x2 + row * H + base + 4) = b;
    float ss = a.x*a.x + a.y*a.y + a.z*a.z + a.w*a.w
             + b.x*b.x + b.y*b.y + b.z*b.z + b.w*b.w;
#pragma unroll
    for (int m = 32; m > 0; m >>= 1) ss += __shfl_xor(ss, m);
    __shared__ float red[4];
    if ((threadIdx.x & 63) == 0) red[threadIdx.x >> 6] = ss;
    __syncthreads();
    float tot = red[0] + red[1] + red[2] + red[3];
    float rs = rsqrtf(tot * (1.0f / H) + 1e-5f);
    float4 wa = *(const float4*)(w + base);
    float4 wb = *(const float4*)(w + base + 4);
    bf16x8 ov;
    ov[0] = (bf16)(a.x * rs * wa.x); ov[1] = (bf16)(a.y * rs * wa.y);
    ov[2] = (bf16)(a.z * rs * wa.z); ov[3] = (bf16)(a.w * rs * wa.w);
    ov[4] = (bf16)(b.x * rs * wb.x); ov[5] = (bf16)(b.y * rs * wb.y);
    ov[6] = (bf16)(b.z * rs * wb.z); ov[7] = (bf16)(b.w * rs * wb.w);
    *(bf16x8*)(hb + row * H + base) = ov;
}

// ---- QKV split-K reduce + scatter to qb/kb/vb ----------------------------
__global__ __launch_bounds__(256) void k_qkvfin(const float* __restrict__ parts,
        bf16* __restrict__ qb, bf16* __restrict__ kb, bf16* __restrict__ vb) {
    int s = blockIdx.x;
    int col = blockIdx.y * 1024 + threadIdx.x * 4;
    const float* p0 = parts + (size_t)s * 3072 + col;
    const float* p1 = p0 + (size_t)2048 * 3072;
    float4 a = *(const float4*)p0;
    float4 b = *(const float4*)p1;
    a.x += b.x; a.y += b.y; a.z += b.z; a.w += b.w;
    bf16x4 o;
    o[0] = (bf16)a.x; o[1] = (bf16)a.y; o[2] = (bf16)a.z; o[3] = (bf16)a.w;
    if (col < 2048)      *(bf16x4*)(qb + (size_t)s * 2048 + col) = o;
    else if (col < 2560) *(bf16x4*)(kb + (size_t)s * 512 + col - 2048) = o;
    else                 *(bf16x4*)(vb + (size_t)s * 512 + col - 2560) = o;
}

// ------------- RoPE + qk-norm, in-place on q (S x 2048) / k (S x 512) -----
__global__ __launch_bounds__(64) void k_rope(bf16* __restrict__ q,
        bf16* __restrict__ k) {
    int s = blockIdx.x, hid = blockIdx.y, lane = threadIdx.x;
    bf16* p;
    if (hid < 16) p = q + (size_t)s * 2048 + hid * 128;
    else          p = k + (size_t)s * 512 + (hid - 16) * 128;
    float x1 = (float)p[lane], x2 = (float)p[lane + 64];
    float f = exp2f((float)lane * -0.2076205059304601f);  // 10000^(-lane/64)
    float sn, cs;
    sincosf((float)s * f, &sn, &cs);
    float o1 = x1 * cs - x2 * sn;
    float o2 = x2 * cs + x1 * sn;
    float ss = o1 * o1 + o2 * o2;
#pragma unroll
    for (int m = 32; m > 0; m >>= 1) ss += __shfl_xor(ss, m);
    float rs = rsqrtf(ss * (1.0f / 128.0f) + 1e-5f);
    p[lane] = (bf16)(o1 * rs);
    p[lane + 64] = (bf16)(o2 * rs);
}

// ------------- flash attention, GQA 16q/4kv, causal, tanh softcap ---------
// Balanced: block (pi,h) processes q-tiles pi and 31-pi => 33 K-tiles each.
// K/V double-buffered with counted vmcnt(8). Poly-tanh softcap (|y|<=0.227).
// Dynamic LDS 88KB: Q@0(16K), K@16K(2x16K), V@48K(2x16K), P@80K(8K).
__global__ __launch_bounds__(256) void k_attn(const bf16* __restrict__ qg,
        const bf16* __restrict__ kgl, const bf16* __restrict__ vtg,
        bf16* __restrict__ og) {
    extern __shared__ char alds[];
    int pi = blockIdx.x, h = blockIdx.y, kvh = h >> 2;
    int tid = threadIdx.x, wave = tid >> 6, lane = tid & 63;
    int lr = lane & 15, kgrp = lane >> 4;

    int rowQ[4], colQ[4], rowV[4], colV[4];
#pragma unroll
    for (int j = 0; j < 4; j++) {
        int p = j * 4096 + wave * 1024 + lane * 16;
        int ps = p ^ (((p >> 8) & 7) << 4);
        rowQ[j] = ps >> 8; colQ[j] = ps & 255;
        int pv = p ^ (((p >> 7) & 7) << 4);
        rowV[j] = pv >> 7; colV[j] = pv & 127;
    }

    const float C1 = 0.08838834764831845f / 50.0f;  // 1/(50*sqrt(128))
    const float L2E50 = 72.13475204444817f;         // 50*log2(e)

#pragma unroll 1
    for (int half = 0; half < 2; ++half) {
        int qt = half ? (31 - pi) : pi;
        int nt = qt + 1;

#pragma unroll
        for (int j = 0; j < 4; j++)
            GLP16((const char*)qg + (size_t)(qt * 64 + rowQ[j]) * 4096 + h * 256 + colQ[j],
                  alds + j * 4096 + wave * 1024);
        for (int t = 0; t < 2 && t < nt; t++) {
#pragma unroll
            for (int j = 0; j < 4; j++)
                GLP16((const char*)kgl + (size_t)(t * 64 + rowQ[j]) * 1024 + kvh * 256 + colQ[j],
                      alds + 16384 + t * 16384 + j * 4096 + wave * 1024);
#pragma unroll
            for (int j = 0; j < 4; j++)
                GLP16((const char*)vtg + (size_t)(kvh * 128 + rowV[j]) * 4096 + t * 128 + colV[j],
                      alds + 49152 + t * 16384 + j * 4096 + wave * 1024);
        }
        if (nt > 1) asm volatile("s_waitcnt vmcnt(8)" ::: "memory");
        else        asm volatile("s_waitcnt vmcnt(0)" ::: "memory");
        __builtin_amdgcn_s_barrier();

        bf16x8 qf[4];
#pragma unroll
        for (int c = 0; c < 4; c++) {
            int b = (wave * 16 + lr) * 256 + c * 64 + kgrp * 16;
            qf[c] = *(const bf16x8*)(alds + (b ^ (((b >> 8) & 7) << 4)));
        }
        f32x4 accO[8];
#pragma unroll
        for (int n = 0; n < 8; n++) accO[n] = (f32x4){0, 0, 0, 0};
        float lsum[4] = {0, 0, 0, 0};
        int qrow = qt * 64 + wave * 16 + kgrp * 4;

        for (int kt = 0; kt < nt; kt++) {
            int buf = kt & 1;
            const char* Kb = alds + 16384 + buf * 16384;
            const char* Vb = alds + 49152 + buf * 16384;
            char* Pb = alds + 81920;
#pragma unroll
            for (int j = 0; j < 4; j++) {
                f32x4 s = {0, 0, 0, 0};
#pragma unroll
                for (int c = 0; c < 4; c++) {
                    int b = (j * 16 + lr) * 256 + c * 64 + kgrp * 16;
                    bf16x8 kf = *(const bf16x8*)(Kb + (b ^ (((b >> 8) & 7) << 4)));
                    s = mfma16(qf[c], kf, s);
                }
                int key = kt * 64 + j * 16 + lr;
#pragma unroll
                for (int r = 0; r < 4; r++) {
                    float y = s[r] * C1;
                    float y2 = y * y;
                    float u = fmaf(y2, 0.13333333f, -0.33333333f);
                    u = fmaf(y2, u, 1.0f);
                    float t5 = y * u;                       // tanh(y)
                    float pe = fmaf(t5, L2E50, -L2E50);     // (50t-50)*log2e
                    float pv = (key <= qrow + r) ? exp2f(pe) : 0.0f;
                    lsum[r] += pv;
                    int wb = (wave * 16 + kgrp * 4 + r) * 128 + (j * 16 + lr) * 2;
                    *(bf16*)(Pb + (wb ^ (((wb >> 7) & 7) << 4))) = (bf16)pv;
                }
            }
            bf16x8 pf[2];
#pragma unroll
            for (int ks2 = 0; ks2 < 2; ks2++) {
                int b = (wave * 16 + lr) * 128 + ks2 * 64 + kgrp * 16;
                pf[ks2] = *(const bf16x8*)(Pb + (b ^ (((b >> 7) & 7) << 4)));
            }
#pragma unroll
            for (int n = 0; n < 8; n++)
#pragma unroll
                for (int ks2 = 0; ks2 < 2; ks2++) {
                    int b = (n * 16 + lr) * 128 + ks2 * 64 + kgrp * 16;
                    bf16x8 vf = *(const bf16x8*)(Vb + (b ^ (((b >> 7) & 7) << 4)));
                    accO[n] = mfma16(pf[ks2], vf, accO[n]);
                }
            __builtin_amdgcn_s_barrier();
            bool more = (kt + 2 < nt);
            if (more) {
                int t = kt + 2;
#pragma unroll
                for (int j = 0; j < 4; j++)
                    GLP16((const char*)kgl + (size_t)(t * 64 + rowQ[j]) * 1024 + kvh * 256 + colQ[j],
                          alds + 16384 + buf * 16384 + j * 4096 + wave * 1024);
#pragma unroll
                for (int j = 0; j < 4; j++)
                    GLP16((const char*)vtg + (size_t)(kvh * 128 + rowV[j]) * 4096 + t * 128 + colV[j],
                          alds + 49152 + buf * 16384 + j * 4096 + wave * 1024);
            }
            if (kt + 1 < nt) {
                if (more) asm volatile("s_waitcnt vmcnt(8)" ::: "memory");
                else      asm volatile("s_waitcnt vmcnt(0)" ::: "memory");
                __builtin_amdgcn_s_barrier();
            }
        }
#pragma unroll
        for (int r = 0; r < 4; r++) {
            float t = lsum[r];
            t += __shfl_xor(t, 1); t += __shfl_xor(t, 2);
            t += __shfl_xor(t, 4); t += __shfl_xor(t, 8);
            lsum[r] = t;
        }
#pragma unroll
        for (int n = 0; n < 8; n++)
#pragma unroll
            for (int r = 0; r < 4; r++) {
                size_t row = qt * 64 + wave * 16 + kgrp * 4 + r;
                og[row * 2048 + h * 128 + n * 16 + lr] = (bf16)(accO[n][r] / lsum[r]);
            }
    }
}

// --------------------------------------------------------------------------
extern "C" void kernel_launch(void* const* d_in, const int* in_sizes, int n_in,
                              void* d_out, int out_size, void* d_ws, size_t ws_size,
                              hipStream_t stream) {
    const float* x      = (const float*)d_in[0];
    const float* attn_w = (const float*)d_in[1];
    const float* mlp_w  = (const float*)d_in[2];
    const float* wq     = (const float*)d_in[3];
    const float* wk     = (const float*)d_in[4];
    const float* wv     = (const float*)d_in[5];
    const float* wo     = (const float*)d_in[6];
    const float* wgate  = (const float*)d_in[7];
    const float* wup    = (const float*)d_in[8];
    const float* wdown  = (const float*)d_in[9];
    float* out = (float*)d_out;
    char* ws = (char*)d_ws;

    const size_t MB = 1024 * 1024;
    bf16* W1  = (bf16*)(ws + 0);        // wqkvT (12.6MB), later wgateT (32MB)
    bf16* W2  = (bf16*)(ws + 32 * MB);  // woT, wupT
    bf16* W3  = (bf16*)(ws + 64 * MB);  // wdownT
    bf16* hb  = (bf16*)(ws + 96 * MB);  // 8MB: h, later h2
    bf16* qb  = (bf16*)(ws + 104 * MB); // 8MB
    bf16* kb  = (bf16*)(ws + 112 * MB); // 2MB
    bf16* vb  = (bf16*)(ws + 114 * MB); // 2MB
    bf16* ob  = (bf16*)(ws + 116 * MB); // 8MB
    float* x2 = (float*)(ws + 124 * MB);// 16MB
    bf16* gb  = (bf16*)(ws + 140 * MB); // 32MB (gate, then silu(g)*u in place)
    bf16* vt  = (bf16*)(ws + 0);        // 2MB, aliases W1 (wqkvT dead by then)
    float* parts = (float*)(ws + 0);    // split-K partials: O 32MB, down 64MB
    float* partsq = (float*)(ws + 116 * MB); // QKV partials 50.3MB (116-166MB)

    const int LDS3 = 131072;
    hipFuncSetAttribute((const void*)&k_gemm3<0>,
        hipFuncAttributeMaxDynamicSharedMemorySize, LDS3);
    hipFuncSetAttribute((const void*)&k_gemm3<2>,
        hipFuncAttributeMaxDynamicSharedMemorySize, LDS3);
    hipFuncSetAttribute((const void*)&k_gemm3<3>,
        hipFuncAttributeMaxDynamicSharedMemorySize, LDS3);
    const int LDSA = 90112;
    hipFuncSetAttribute((const void*)&k_attn,
        hipFuncAttributeMaxDynamicSharedMemorySize, LDSA);

    dim3 cb(32, 8);
    const size_t n4 = (size_t)2048 * 2048 / 4;

    // 1. attn RMSNorm
    k_rmsnorm<<<2048, 256, 0, stream>>>(x, attn_w, hb);
    // 2. convert QKV weights into one [3072][2048] bf16 Bt
    k_convT<<<dim3(64, 64), cb, 0, stream>>>(wq, W1, 2048, 2048);
    k_convT<<<dim3(64, 16), cb, 0, stream>>>(wk, W1 + 4194304, 2048, 512);
    k_convT<<<dim3(64, 16), cb, 0, stream>>>(wv, W1 + 5242880, 2048, 512);
    // 3. fused QKV projection, split-K=2 -> fp32 partials; reduce+scatter
    k_gemm3<3><<<dim3(12, 8, 2), 512, LDS3, stream>>>(hb, W1, partsq, nullptr,
                                                      2048, 3072, 2048, 1024);
    k_qkvfin<<<dim3(2048, 3), 256, 0, stream>>>(partsq, qb, kb, vb);
    // 4. V transpose (vb[2048][512] -> vt[512][2048]); wqkvT dead now
    k_transpose<<<dim3(64, 16), 256, 0, stream>>>(vb, vt, 2048, 512);
    // 5. RoPE + qk-norm (in place)
    k_rope<<<dim3(2048, 20), 64, 0, stream>>>(qb, kb);
    // 6. attention (balanced pairing)
    k_attn<<<dim3(16, 16), 256, LDSA, stream>>>(qb, kb, vt, ob);
    // 7. O projection, split-K=2 -> fp32 partials; fused reduce+rmsnorm
    k_convT<<<dim3(64, 64), cb, 0, stream>>>(wo, W2, 2048, 2048);
    k_gemm3<3><<<dim3(8, 8, 2), 512, LDS3, stream>>>(ob, W2, parts, nullptr,
                                                     2048, 2048, 2048, 1024);
    k_reduce_rms<<<2048, 256, 0, stream>>>(parts, x, mlp_w, x2, hb, 2);
    // 8. gate GEMM
    k_convT<<<dim3(64, 256), cb, 0, stream>>>(wgate, W1, 2048, 8192);
    k_gemm3<0><<<dim3(32, 8, 1), 512, LDS3, stream>>>(hb, W1, gb, nullptr,
                                                      2048, 8192, 2048, 2048);
    // 9. up GEMM with silu(gate)*up epilogue (in place over gb)
    k_convT<<<dim3(64, 256), cb, 0, stream>>>(wup, W2, 2048, 8192);
    k_gemm3<2><<<dim3(32, 8, 1), 512, LDS3, stream>>>(hb, W2, gb, gb,
                                                      2048, 8192, 2048, 2048);
    // 10. down GEMM, split-K=4 -> partials; reduce + residual -> out
    k_convT<<<dim3(256, 64), cb, 0, stream>>>(wdown, W3, 8192, 2048);
    k_gemm3<3><<<dim3(8, 8, 4), 512, LDS3, stream>>>(gb, W3, parts, nullptr,
                                                     2048, 2048, 8192, 2048);
    k_reduce<<<4096, 256, 0, stream>>>(parts, x2, out, 4, n4);
}

// Round 6
// 473.570 us; speedup vs baseline: 1.0340x; 1.0340x over previous
//
#include <hip/hip_runtime.h>

typedef __bf16 bf16;
typedef __bf16 bf16x4 __attribute__((ext_vector_type(4)));
typedef __bf16 bf16x8 __attribute__((ext_vector_type(8)));
typedef float f32x4 __attribute__((ext_vector_type(4)));

#define GLP16(gp, lp) __builtin_amdgcn_global_load_lds( \
    (const __attribute__((address_space(1))) void*)(gp), \
    (__attribute__((address_space(3))) void*)(lp), 16, 0, 0)

__device__ __forceinline__ f32x4 mfma16(bf16x8 a, bf16x8 b, f32x4 c) {
    return __builtin_amdgcn_mfma_f32_16x16x32_bf16(a, b, c, 0, 0, 0);
}

// ---------------- RMSNorm: fp32 in -> bf16 out, row = 2048 ----------------
__global__ __launch_bounds__(256) void k_rmsnorm(const float* __restrict__ x,
        const float* __restrict__ w, bf16* __restrict__ out) {
    const int H = 2048;
    size_t row = blockIdx.x;
    const float* xr = x + row * H;
    int base = threadIdx.x * 8;
    float4 a = *(const float4*)(xr + base);
    float4 b = *(const float4*)(xr + base + 4);
    float ss = a.x*a.x + a.y*a.y + a.z*a.z + a.w*a.w
             + b.x*b.x + b.y*b.y + b.z*b.z + b.w*b.w;
#pragma unroll
    for (int m = 32; m > 0; m >>= 1) ss += __shfl_xor(ss, m);
    __shared__ float red[4];
    if ((threadIdx.x & 63) == 0) red[threadIdx.x >> 6] = ss;
    __syncthreads();
    float tot = red[0] + red[1] + red[2] + red[3];
    float rs = rsqrtf(tot * (1.0f / H) + 1e-5f);
    float4 wa = *(const float4*)(w + base);
    float4 wb = *(const float4*)(w + base + 4);
    bf16x8 ov;
    ov[0] = (bf16)(a.x * rs * wa.x); ov[1] = (bf16)(a.y * rs * wa.y);
    ov[2] = (bf16)(a.z * rs * wa.z); ov[3] = (bf16)(a.w * rs * wa.w);
    ov[4] = (bf16)(b.x * rs * wb.x); ov[5] = (bf16)(b.y * rs * wb.y);
    ov[6] = (bf16)(b.z * rs * wb.z); ov[7] = (bf16)(b.w * rs * wb.w);
    *(bf16x8*)(out + row * H + base) = ov;
}

// ------- convert + transpose: W (K x N fp32) -> Wt (N x K bf16) -----------
__global__ __launch_bounds__(256) void k_convT(const float* __restrict__ W,
        bf16* __restrict__ Wt, int K, int N) {
    __shared__ float t[32][33];
    int k0 = blockIdx.x * 32, n0 = blockIdx.y * 32;
    int tx = threadIdx.x, ty = threadIdx.y;
#pragma unroll
    for (int i = 0; i < 4; i++)
        t[ty + i * 8][tx] = W[(size_t)(k0 + ty + i * 8) * N + n0 + tx];
    __syncthreads();
#pragma unroll
    for (int i = 0; i < 4; i++)
        Wt[(size_t)(n0 + ty + i * 8) * K + k0 + tx] = (bf16)t[tx][ty + i * 8];
}

// ------- bf16 transpose: in (R x C) -> out (C x R) ------------------------
__global__ __launch_bounds__(256) void k_transpose(const bf16* __restrict__ in,
        bf16* __restrict__ out, int R, int C) {
    __shared__ bf16 t[32][33];
    int r0 = blockIdx.x * 32, c0 = blockIdx.y * 32;
    int tx = threadIdx.x & 31, ty = threadIdx.x >> 5;
#pragma unroll
    for (int i = 0; i < 4; i++)
        t[ty + i * 8][tx] = in[(size_t)(r0 + ty + i * 8) * C + c0 + tx];
    __syncthreads();
#pragma unroll
    for (int i = 0; i < 4; i++)
        out[(size_t)(c0 + ty + i * 8) * R + r0 + tx] = t[tx][ty + i * 8];
}

// ---------------- GEMM v4: m201 8-phase template port ---------------------
// BM=BN=256, BK=64, 2 K-tiles/iter, 8 waves (2M x 4N), per-wave 128x64.
// Wave M rows = {wm*64..+63} u {128+wm*64..+63}; N cols = {wn*32..+31} u
// {128+wn*32..+31} -> each phase reads exactly one half-tile class.
// LDS 128KB: A buf0@0, A buf1@32K, B buf0@64K, B buf1@96K; half = 16KB,
// rows of 128B, XOR-swizzled byte^=((row&7)<<4) (2-way = free). GLP dest
// linear, source pre-swizzled (rule 21).
// Phases (tile t=even in buf0, t+1 in buf1), quadrant (mh,nh):
//  P1 (0,0): rd A-h0,B-h0(buf0); stage A-h1(t+1)
//  P2 (0,1): rd B-h1(buf0);      stage A-h0(t+2)
//  P3 (1,1): rd A-h1(buf0);      stage B-h0(t+2)
//  P4 (1,0): no reads;           stage B-h1(t+2); vmcnt(6)
//  P5-P8: same on buf1, staging A-h1(t+2), A-h0/B-h0/B-h1(t+3); vmcnt(6)@P8
// Each half-tile staged >=4 phases before first read; slot free >=1 phase
// before stage; vmcnt(6) = 3 half-tiles in flight. Final iter: vmcnt(0)@P4.
// EPI: 0 = bf16 store, 2 = silu(aux)*acc -> bf16, 3 = fp32 partial (split-K)
template<int EPI>
__global__ __launch_bounds__(512, 2) void k_gemm4(const bf16* __restrict__ A,
        const bf16* __restrict__ Bt, void* __restrict__ outp,
        const void* __restrict__ aux, int M, int N, int K, int ksplit) {
    extern __shared__ char lds[];
    const int tid = threadIdx.x, wave = tid >> 6, lane = tid & 63;
    const int lr = lane & 15, kg = lane >> 4;
    const int wm = wave >> 2, wn = wave & 3;
    const int bn = blockIdx.x, bm = blockIdx.y, split = blockIdx.z;
    const int row0 = bm * 256, col0 = bn * 256;
    const int kbeg = split * ksplit;
    const int NT = ksplit >> 6;          // K-tiles of 64
    const size_t K2 = (size_t)K * 2;
    const int xorm = (lr & 7) << 4;

    char* const A0 = lds;
    char* const A1 = lds + 32768;
    char* const B0 = lds + 65536;
    char* const B1 = lds + 98304;

    // staging: dest byte d in 16KB half -> pre-swizzled source offset
    size_t soff[2];
#pragma unroll
    for (int s = 0; s < 2; s++) {
        int d = s * 8192 + tid * 16;
        int rh = d >> 7, c = d & 127;
        soff[s] = (size_t)rh * K2 + (c ^ ((rh & 7) << 4));
    }
    const char* Ab = (const char*)A + ((size_t)row0 * K + kbeg) * 2;
    const char* Bb = (const char*)Bt + ((size_t)col0 * K + kbeg) * 2;

    auto stA = [&](int t, int mh) {
        const char* src = Ab + (size_t)(mh * 128) * K2 + (size_t)t * 128;
        char* dst = lds + (t & 1) * 32768 + mh * 16384 + wave * 1024;
        GLP16(src + soff[0], dst);
        GLP16(src + soff[1], dst + 8192);
    };
    auto stB = [&](int t, int nh) {
        const char* src = Bb + (size_t)(nh * 128) * K2 + (size_t)t * 128;
        char* dst = lds + 65536 + (t & 1) * 32768 + nh * 16384 + wave * 1024;
        GLP16(src + soff[0], dst);
        GLP16(src + soff[1], dst + 8192);
    };

    f32x4 acc[8][4];
#pragma unroll
    for (int m = 0; m < 8; m++)
#pragma unroll
        for (int n = 0; n < 4; n++) acc[m][n] = (f32x4){0, 0, 0, 0};

    bf16x8 a[8], c0[4], c1[4];
    auto rdA = [&](const char* base, int mh) {
#pragma unroll
        for (int mi = 0; mi < 4; mi++)
#pragma unroll
            for (int kk = 0; kk < 2; kk++) {
                int rh = wm * 64 + mi * 16 + lr;
                int c = (kk * 64 + kg * 16) ^ xorm;
                a[mi * 2 + kk] = *(const bf16x8*)(base + mh * 16384 + rh * 128 + c);
            }
    };
    auto rdB = [&](const char* base, int nh, bf16x8 (&b)[4]) {
#pragma unroll
        for (int nj = 0; nj < 2; nj++)
#pragma unroll
            for (int kk = 0; kk < 2; kk++) {
                int rh = wn * 32 + nj * 16 + lr;
                int c = (kk * 64 + kg * 16) ^ xorm;
                b[nj * 2 + kk] = *(const bf16x8*)(base + nh * 16384 + rh * 128 + c);
            }
    };
    auto mm = [&](int mh, int nh, bf16x8 (&b)[4]) {
#pragma unroll
        for (int mi = 0; mi < 4; mi++)
#pragma unroll
            for (int nj = 0; nj < 2; nj++)
#pragma unroll
                for (int kk = 0; kk < 2; kk++)
                    acc[mh * 4 + mi][nh * 2 + nj] =
                        mfma16(a[mi * 2 + kk], b[nj * 2 + kk],
                               acc[mh * 4 + mi][nh * 2 + nj]);
    };

#define SYNCMM \
    __builtin_amdgcn_sched_barrier(0); \
    __builtin_amdgcn_s_barrier(); \
    asm volatile("s_waitcnt lgkmcnt(0)" ::: "memory"); \
    __builtin_amdgcn_sched_barrier(0); \
    __builtin_amdgcn_s_setprio(1);
#define ENDPH \
    __builtin_amdgcn_s_setprio(0); \
    __builtin_amdgcn_sched_barrier(0); \
    __builtin_amdgcn_s_barrier();

    // prologue: tile0 fully, tile1 all but A-h1 (issue order matters)
    stA(0, 0); stB(0, 0); stB(0, 1); stA(0, 1);
    stA(1, 0); stB(1, 0); stB(1, 1);
    asm volatile("s_waitcnt vmcnt(6)" ::: "memory");
    __builtin_amdgcn_s_barrier();

    const int NIT = NT >> 1;
    for (int it = 0; it < NIT; ++it) {
        const int t = it * 2;
        const bool more = (t + 2 < NT);
        // P1 (0,0) buf0
        rdA(A0, 0); rdB(B0, 0, c0);
        stA(t + 1, 1);
        SYNCMM; mm(0, 0, c0); ENDPH;
        // P2 (0,1)
        rdB(B0, 1, c1);
        if (more) stA(t + 2, 0);
        SYNCMM; mm(0, 1, c1); ENDPH;
        // P3 (1,1)
        rdA(A0, 1);
        if (more) stB(t + 2, 0);
        SYNCMM; mm(1, 1, c1); ENDPH;
        // P4 (1,0) -- no reads
        if (more) stB(t + 2, 1);
        __builtin_amdgcn_sched_barrier(0);
        __builtin_amdgcn_s_barrier();
        __builtin_amdgcn_s_setprio(1);
        mm(1, 0, c0);
        __builtin_amdgcn_s_setprio(0);
        if (more) asm volatile("s_waitcnt vmcnt(6)" ::: "memory");
        else      asm volatile("s_waitcnt vmcnt(0)" ::: "memory");
        __builtin_amdgcn_sched_barrier(0);
        __builtin_amdgcn_s_barrier();
        // P5 (0,0) buf1
        rdA(A1, 0); rdB(B1, 0, c0);
        if (more) stA(t + 2, 1);
        SYNCMM; mm(0, 0, c0); ENDPH;
        // P6 (0,1)
        rdB(B1, 1, c1);
        if (t + 3 < NT) stA(t + 3, 0);
        SYNCMM; mm(0, 1, c1); ENDPH;
        // P7 (1,1)
        rdA(A1, 1);
        if (t + 3 < NT) stB(t + 3, 0);
        SYNCMM; mm(1, 1, c1); ENDPH;
        // P8 (1,0)
        if (t + 3 < NT) stB(t + 3, 1);
        __builtin_amdgcn_sched_barrier(0);
        __builtin_amdgcn_s_barrier();
        __builtin_amdgcn_s_setprio(1);
        mm(1, 0, c0);
        __builtin_amdgcn_s_setprio(0);
        if (more) asm volatile("s_waitcnt vmcnt(6)" ::: "memory");
        __builtin_amdgcn_sched_barrier(0);
        __builtin_amdgcn_s_barrier();
    }
#undef SYNCMM
#undef ENDPH

#pragma unroll
    for (int mi = 0; mi < 8; mi++)
#pragma unroll
        for (int ni = 0; ni < 4; ni++)
#pragma unroll
            for (int r = 0; r < 4; r++) {
                size_t row = row0 + (mi >> 2) * 128 + wm * 64 + (mi & 3) * 16 + kg * 4 + r;
                size_t col = col0 + (ni >> 1) * 128 + wn * 32 + (ni & 1) * 16 + lr;
                size_t idx = row * N + col;
                float vv = acc[mi][ni][r];
                if (EPI == 0) {
                    ((bf16*)outp)[idx] = (bf16)vv;
                } else if (EPI == 2) {
                    float g = (float)((const bf16*)aux)[idx];
                    float sg = g / (1.0f + __expf(-g));
                    ((bf16*)outp)[idx] = (bf16)(sg * vv);
                } else {
                    ((float*)outp)[(size_t)split * M * N + idx] = vv;
                }
            }
}

// ---- reduce: out = resid + sum_s parts[s], fp32, vectorized float4 -------
__global__ __launch_bounds__(256) void k_reduce(const float* __restrict__ parts,
        const float* __restrict__ resid, float* __restrict__ out,
        int ns, size_t n4) {
    size_t i = (size_t)blockIdx.x * 256 + threadIdx.x;
    if (i >= n4) return;
    float4 acc = ((const float4*)resid)[i];
    for (int s = 0; s < ns; s++) {
        float4 p = ((const float4*)(parts + (size_t)s * n4 * 4))[i];
        acc.x += p.x; acc.y += p.y; acc.z += p.z; acc.w += p.w;
    }
    ((float4*)out)[i] = acc;
}

// ---- fused: x2 = resid + sum parts; hb = rmsnorm(x2)*w  (row = 2048) -----
__global__ __launch_bounds__(256) void k_reduce_rms(const float* __restrict__ parts,
        const float* __restrict__ resid, const float* __restrict__ w,
        float* __restrict__ x2, bf16* __restrict__ hb, int ns) {
    const int H = 2048;
    size_t row = blockIdx.x;
    int base = threadIdx.x * 8;
    const float* rr = resid + row * H + base;
    float4 a = *(const float4*)rr;
    float4 b = *(const float4*)(rr + 4);
    for (int s = 0; s < ns; s++) {
        const float* pp = parts + (size_t)s * H * 2048 + row * H + base;
        float4 pa = *(const float4*)pp;
        float4 pb = *(const float4*)(pp + 4);
        a.x += pa.x; a.y += pa.y; a.z += pa.z; a.w += pa.w;
        b.x += pb.x; b.y += pb.y; b.z += pb.z; b.w += pb.w;
    }
    *(float4*)(x2 + row * H + base) = a;
    *(float4*)(x2 + row * H + base + 4) = b;
    float ss = a.x*a.x + a.y*a.y + a.z*a.z + a.w*a.w
             + b.x*b.x + b.y*b.y + b.z*b.z + b.w*b.w;
#pragma unroll
    for (int m = 32; m > 0; m >>= 1) ss += __shfl_xor(ss, m);
    __shared__ float red[4];
    if ((threadIdx.x & 63) == 0) red[threadIdx.x >> 6] = ss;
    __syncthreads();
    float tot = red[0] + red[1] + red[2] + red[3];
    float rs = rsqrtf(tot * (1.0f / H) + 1e-5f);
    float4 wa = *(const float4*)(w + base);
    float4 wb = *(const float4*)(w + base + 4);
    bf16x8 ov;
    ov[0] = (bf16)(a.x * rs * wa.x); ov[1] = (bf16)(a.y * rs * wa.y);
    ov[2] = (bf16)(a.z * rs * wa.z); ov[3] = (bf16)(a.w * rs * wa.w);
    ov[4] = (bf16)(b.x * rs * wb.x); ov[5] = (bf16)(b.y * rs * wb.y);
    ov[6] = (bf16)(b.z * rs * wb.z); ov[7] = (bf16)(b.w * rs * wb.w);
    *(bf16x8*)(hb + row * H + base) = ov;
}

// ---- QKV split-K reduce + scatter to qb/kb/vb ----------------------------
__global__ __launch_bounds__(256) void k_qkvfin(const float* __restrict__ parts,
        bf16* __restrict__ qb, bf16* __restrict__ kb, bf16* __restrict__ vb) {
    int s = blockIdx.x;
    int col = blockIdx.y * 1024 + threadIdx.x * 4;
    const float* p0 = parts + (size_t)s * 3072 + col;
    const float* p1 = p0 + (size_t)2048 * 3072;
    float4 a = *(const float4*)p0;
    float4 b = *(const float4*)p1;
    a.x += b.x; a.y += b.y; a.z += b.z; a.w += b.w;
    bf16x4 o;
    o[0] = (bf16)a.x; o[1] = (bf16)a.y; o[2] = (bf16)a.z; o[3] = (bf16)a.w;
    if (col < 2048)      *(bf16x4*)(qb + (size_t)s * 2048 + col) = o;
    else if (col < 2560) *(bf16x4*)(kb + (size_t)s * 512 + col - 2048) = o;
    else                 *(bf16x4*)(vb + (size_t)s * 512 + col - 2560) = o;
}

// ------------- RoPE + qk-norm, in-place on q (S x 2048) / k (S x 512) -----
__global__ __launch_bounds__(64) void k_rope(bf16* __restrict__ q,
        bf16* __restrict__ k) {
    int s = blockIdx.x, hid = blockIdx.y, lane = threadIdx.x;
    bf16* p;
    if (hid < 16) p = q + (size_t)s * 2048 + hid * 128;
    else          p = k + (size_t)s * 512 + (hid - 16) * 128;
    float x1 = (float)p[lane], x2 = (float)p[lane + 64];
    float f = exp2f((float)lane * -0.2076205059304601f);  // 10000^(-lane/64)
    float sn, cs;
    sincosf((float)s * f, &sn, &cs);
    float o1 = x1 * cs - x2 * sn;
    float o2 = x2 * cs + x1 * sn;
    float ss = o1 * o1 + o2 * o2;
#pragma unroll
    for (int m = 32; m > 0; m >>= 1) ss += __shfl_xor(ss, m);
    float rs = rsqrtf(ss * (1.0f / 128.0f) + 1e-5f);
    p[lane] = (bf16)(o1 * rs);
    p[lane + 64] = (bf16)(o2 * rs);
}

// ------------- flash attention, GQA 16q/4kv, causal, tanh softcap ---------
// Balanced: block (pi,h) processes q-tiles pi and 31-pi => 33 K-tiles each.
// K/V double-buffered with counted vmcnt(8). Poly-tanh softcap (|y|<=0.227).
// Dynamic LDS 88KB: Q@0(16K), K@16K(2x16K), V@48K(2x16K), P@80K(8K).
__global__ __launch_bounds__(256) void k_attn(const bf16* __restrict__ qg,
        const bf16* __restrict__ kgl, const bf16* __restrict__ vtg,
        bf16* __restrict__ og) {
    extern __shared__ char alds[];
    int pi = blockIdx.x, h = blockIdx.y, kvh = h >> 2;
    int tid = threadIdx.x, wave = tid >> 6, lane = tid & 63;
    int lr = lane & 15, kgrp = lane >> 4;

    int rowQ[4], colQ[4], rowV[4], colV[4];
#pragma unroll
    for (int j = 0; j < 4; j++) {
        int p = j * 4096 + wave * 1024 + lane * 16;
        int ps = p ^ (((p >> 8) & 7) << 4);
        rowQ[j] = ps >> 8; colQ[j] = ps & 255;
        int pv = p ^ (((p >> 7) & 7) << 4);
        rowV[j] = pv >> 7; colV[j] = pv & 127;
    }

    const float C1 = 0.08838834764831845f / 50.0f;  // 1/(50*sqrt(128))
    const float L2E50 = 72.13475204444817f;         // 50*log2(e)

#pragma unroll 1
    for (int half = 0; half < 2; ++half) {
        int qt = half ? (31 - pi) : pi;
        int nt = qt + 1;

#pragma unroll
        for (int j = 0; j < 4; j++)
            GLP16((const char*)qg + (size_t)(qt * 64 + rowQ[j]) * 4096 + h * 256 + colQ[j],
                  alds + j * 4096 + wave * 1024);
        for (int t = 0; t < 2 && t < nt; t++) {
#pragma unroll
            for (int j = 0; j < 4; j++)
                GLP16((const char*)kgl + (size_t)(t * 64 + rowQ[j]) * 1024 + kvh * 256 + colQ[j],
                      alds + 16384 + t * 16384 + j * 4096 + wave * 1024);
#pragma unroll
            for (int j = 0; j < 4; j++)
                GLP16((const char*)vtg + (size_t)(kvh * 128 + rowV[j]) * 4096 + t * 128 + colV[j],
                      alds + 49152 + t * 16384 + j * 4096 + wave * 1024);
        }
        if (nt > 1) asm volatile("s_waitcnt vmcnt(8)" ::: "memory");
        else        asm volatile("s_waitcnt vmcnt(0)" ::: "memory");
        __builtin_amdgcn_s_barrier();

        bf16x8 qf[4];
#pragma unroll
        for (int c = 0; c < 4; c++) {
            int b = (wave * 16 + lr) * 256 + c * 64 + kgrp * 16;
            qf[c] = *(const bf16x8*)(alds + (b ^ (((b >> 8) & 7) << 4)));
        }
        f32x4 accO[8];
#pragma unroll
        for (int n = 0; n < 8; n++) accO[n] = (f32x4){0, 0, 0, 0};
        float lsum[4] = {0, 0, 0, 0};
        int qrow = qt * 64 + wave * 16 + kgrp * 4;

        for (int kt = 0; kt < nt; kt++) {
            int buf = kt & 1;
            const char* Kb = alds + 16384 + buf * 16384;
            const char* Vb = alds + 49152 + buf * 16384;
            char* Pb = alds + 81920;
#pragma unroll
            for (int j = 0; j < 4; j++) {
                f32x4 s = {0, 0, 0, 0};
#pragma unroll
                for (int c = 0; c < 4; c++) {
                    int b = (j * 16 + lr) * 256 + c * 64 + kgrp * 16;
                    bf16x8 kf = *(const bf16x8*)(Kb + (b ^ (((b >> 8) & 7) << 4)));
                    s = mfma16(qf[c], kf, s);
                }
                int key = kt * 64 + j * 16 + lr;
#pragma unroll
                for (int r = 0; r < 4; r++) {
                    float y = s[r] * C1;
                    float y2 = y * y;
                    float u = fmaf(y2, 0.13333333f, -0.33333333f);
                    u = fmaf(y2, u, 1.0f);
                    float t5 = y * u;                       // tanh(y)
                    float pe = fmaf(t5, L2E50, -L2E50);     // (50t-50)*log2e
                    float pv = (key <= qrow + r) ? exp2f(pe) : 0.0f;
                    lsum[r] += pv;
                    int wb = (wave * 16 + kgrp * 4 + r) * 128 + (j * 16 + lr) * 2;
                    *(bf16*)(Pb + (wb ^ (((wb >> 7) & 7) << 4))) = (bf16)pv;
                }
            }
            bf16x8 pf[2];
#pragma unroll
            for (int ks2 = 0; ks2 < 2; ks2++) {
                int b = (wave * 16 + lr) * 128 + ks2 * 64 + kgrp * 16;
                pf[ks2] = *(const bf16x8*)(Pb + (b ^ (((b >> 7) & 7) << 4)));
            }
#pragma unroll
            for (int n = 0; n < 8; n++)
#pragma unroll
                for (int ks2 = 0; ks2 < 2; ks2++) {
                    int b = (n * 16 + lr) * 128 + ks2 * 64 + kgrp * 16;
                    bf16x8 vf = *(const bf16x8*)(Vb + (b ^ (((b >> 7) & 7) << 4)));
                    accO[n] = mfma16(pf[ks2], vf, accO[n]);
                }
            __builtin_amdgcn_s_barrier();
            bool more = (kt + 2 < nt);
            if (more) {
                int t = kt + 2;
#pragma unroll
                for (int j = 0; j < 4; j++)
                    GLP16((const char*)kgl + (size_t)(t * 64 + rowQ[j]) * 1024 + kvh * 256 + colQ[j],
                          alds + 16384 + buf * 16384 + j * 4096 + wave * 1024);
#pragma unroll
                for (int j = 0; j < 4; j++)
                    GLP16((const char*)vtg + (size_t)(kvh * 128 + rowV[j]) * 4096 + t * 128 + colV[j],
                          alds + 49152 + buf * 16384 + j * 4096 + wave * 1024);
            }
            if (kt + 1 < nt) {
                if (more) asm volatile("s_waitcnt vmcnt(8)" ::: "memory");
                else      asm volatile("s_waitcnt vmcnt(0)" ::: "memory");
                __builtin_amdgcn_s_barrier();
            }
        }
#pragma unroll
        for (int r = 0; r < 4; r++) {
            float t = lsum[r];
            t += __shfl_xor(t, 1); t += __shfl_xor(t, 2);
            t += __shfl_xor(t, 4); t += __shfl_xor(t, 8);
            lsum[r] = t;
        }
#pragma unroll
        for (int n = 0; n < 8; n++)
#pragma unroll
            for (int r = 0; r < 4; r++) {
                size_t row = qt * 64 + wave * 16 + kgrp * 4 + r;
                og[row * 2048 + h * 128 + n * 16 + lr] = (bf16)(accO[n][r] / lsum[r]);
            }
    }
}

// --------------------------------------------------------------------------
extern "C" void kernel_launch(void* const* d_in, const int* in_sizes, int n_in,
                              void* d_out, int out_size, void* d_ws, size_t ws_size,
                              hipStream_t stream) {
    const float* x      = (const float*)d_in[0];
    const float* attn_w = (const float*)d_in[1];
    const float* mlp_w  = (const float*)d_in[2];
    const float* wq     = (const float*)d_in[3];
    const float* wk     = (const float*)d_in[4];
    const float* wv     = (const float*)d_in[5];
    const float* wo     = (const float*)d_in[6];
    const float* wgate  = (const float*)d_in[7];
    const float* wup    = (const float*)d_in[8];
    const float* wdown  = (const float*)d_in[9];
    float* out = (float*)d_out;
    char* ws = (char*)d_ws;

    const size_t MB = 1024 * 1024;
    bf16* W1  = (bf16*)(ws + 0);        // wqkvT (12.6MB), later wgateT (32MB)
    bf16* W2  = (bf16*)(ws + 32 * MB);  // woT, wupT
    bf16* W3  = (bf16*)(ws + 64 * MB);  // wdownT
    bf16* hb  = (bf16*)(ws + 96 * MB);  // 8MB: h, later h2
    bf16* qb  = (bf16*)(ws + 104 * MB); // 8MB
    bf16* kb  = (bf16*)(ws + 112 * MB); // 2MB
    bf16* vb  = (bf16*)(ws + 114 * MB); // 2MB
    bf16* ob  = (bf16*)(ws + 116 * MB); // 8MB
    float* x2 = (float*)(ws + 124 * MB);// 16MB
    bf16* gb  = (bf16*)(ws + 140 * MB); // 32MB (gate, then silu(g)*u in place)
    bf16* vt  = (bf16*)(ws + 0);        // 2MB, aliases W1 (wqkvT dead by then)
    float* parts = (float*)(ws + 0);    // split-K partials: O 32MB, down 64MB
    float* partsq = (float*)(ws + 116 * MB); // QKV partials 50.3MB (116-166MB)

    const int LDS4 = 131072;
    hipFuncSetAttribute((const void*)&k_gemm4<0>,
        hipFuncAttributeMaxDynamicSharedMemorySize, LDS4);
    hipFuncSetAttribute((const void*)&k_gemm4<2>,
        hipFuncAttributeMaxDynamicSharedMemorySize, LDS4);
    hipFuncSetAttribute((const void*)&k_gemm4<3>,
        hipFuncAttributeMaxDynamicSharedMemorySize, LDS4);
    const int LDSA = 90112;
    hipFuncSetAttribute((const void*)&k_attn,
        hipFuncAttributeMaxDynamicSharedMemorySize, LDSA);

    dim3 cb(32, 8);
    const size_t n4 = (size_t)2048 * 2048 / 4;

    // 1. attn RMSNorm
    k_rmsnorm<<<2048, 256, 0, stream>>>(x, attn_w, hb);
    // 2. convert QKV weights into one [3072][2048] bf16 Bt
    k_convT<<<dim3(64, 64), cb, 0, stream>>>(wq, W1, 2048, 2048);
    k_convT<<<dim3(64, 16), cb, 0, stream>>>(wk, W1 + 4194304, 2048, 512);
    k_convT<<<dim3(64, 16), cb, 0, stream>>>(wv, W1 + 5242880, 2048, 512);
    // 3. fused QKV projection, split-K=2 -> fp32 partials; reduce+scatter
    k_gemm4<3><<<dim3(12, 8, 2), 512, LDS4, stream>>>(hb, W1, partsq, nullptr,
                                                      2048, 3072, 2048, 1024);
    k_qkvfin<<<dim3(2048, 3), 256, 0, stream>>>(partsq, qb, kb, vb);
    // 4. V transpose (vb[2048][512] -> vt[512][2048]); wqkvT dead now
    k_transpose<<<dim3(64, 16), 256, 0, stream>>>(vb, vt, 2048, 512);
    // 5. RoPE + qk-norm (in place)
    k_rope<<<dim3(2048, 20), 64, 0, stream>>>(qb, kb);
    // 6. attention (balanced pairing)
    k_attn<<<dim3(16, 16), 256, LDSA, stream>>>(qb, kb, vt, ob);
    // 7. O projection, split-K=2 -> fp32 partials; fused reduce+rmsnorm
    k_convT<<<dim3(64, 64), cb, 0, stream>>>(wo, W2, 2048, 2048);
    k_gemm4<3><<<dim3(8, 8, 2), 512, LDS4, stream>>>(ob, W2, parts, nullptr,
                                                     2048, 2048, 2048, 1024);
    k_reduce_rms<<<2048, 256, 0, stream>>>(parts, x, mlp_w, x2, hb, 2);
    // 8. gate GEMM
    k_convT<<<dim3(64, 256), cb, 0, stream>>>(wgate, W1, 2048, 8192);
    k_gemm4<0><<<dim3(32, 8, 1), 512, LDS4, stream>>>(hb, W1, gb, nullptr,
                                                      2048, 8192, 2048, 2048);
    // 9. up GEMM with silu(gate)*up epilogue (in place over gb)
    k_convT<<<dim3(64, 256), cb, 0, stream>>>(wup, W2, 2048, 8192);
    k_gemm4<2><<<dim3(32, 8, 1), 512, LDS4, stream>>>(hb, W2, gb, gb,
                                                      2048, 8192, 2048, 2048);
    // 10. down GEMM, split-K=4 -> partials; reduce + residual -> out
    k_convT<<<dim3(256, 64), cb, 0, stream>>>(wdown, W3, 8192, 2048);
    k_gemm4<3><<<dim3(8, 8, 4), 512, LDS4, stream>>>(gb, W3, parts, nullptr,
                                                     2048, 2048, 8192, 2048);
    k_reduce<<<4096, 256, 0, stream>>>(parts, x2, out, 4, n4);
}

// Round 7
// 466.976 us; speedup vs baseline: 1.0486x; 1.0141x over previous
//
#include <hip/hip_runtime.h>

typedef __bf16 bf16;
typedef __bf16 bf16x4 __attribute__((ext_vector_type(4)));
typedef __bf16 bf16x8 __attribute__((ext_vector_type(8)));
typedef float f32x4 __attribute__((ext_vector_type(4)));

#define GLP16(gp, lp) __builtin_amdgcn_global_load_lds( \
    (const __attribute__((address_space(1))) void*)(gp), \
    (__attribute__((address_space(3))) void*)(lp), 16, 0, 0)

__device__ __forceinline__ f32x4 mfma16(bf16x8 a, bf16x8 b, f32x4 c) {
    return __builtin_amdgcn_mfma_f32_16x16x32_bf16(a, b, c, 0, 0, 0);
}

// ---------------- RMSNorm: fp32 in -> bf16 out, row = 2048 ----------------
__global__ __launch_bounds__(256) void k_rmsnorm(const float* __restrict__ x,
        const float* __restrict__ w, bf16* __restrict__ out) {
    const int H = 2048;
    size_t row = blockIdx.x;
    const float* xr = x + row * H;
    int base = threadIdx.x * 8;
    float4 a = *(const float4*)(xr + base);
    float4 b = *(const float4*)(xr + base + 4);
    float ss = a.x*a.x + a.y*a.y + a.z*a.z + a.w*a.w
             + b.x*b.x + b.y*b.y + b.z*b.z + b.w*b.w;
#pragma unroll
    for (int m = 32; m > 0; m >>= 1) ss += __shfl_xor(ss, m);
    __shared__ float red[4];
    if ((threadIdx.x & 63) == 0) red[threadIdx.x >> 6] = ss;
    __syncthreads();
    float tot = red[0] + red[1] + red[2] + red[3];
    float rs = rsqrtf(tot * (1.0f / H) + 1e-5f);
    float4 wa = *(const float4*)(w + base);
    float4 wb = *(const float4*)(w + base + 4);
    bf16x8 ov;
    ov[0] = (bf16)(a.x * rs * wa.x); ov[1] = (bf16)(a.y * rs * wa.y);
    ov[2] = (bf16)(a.z * rs * wa.z); ov[3] = (bf16)(a.w * rs * wa.w);
    ov[4] = (bf16)(b.x * rs * wb.x); ov[5] = (bf16)(b.y * rs * wb.y);
    ov[6] = (bf16)(b.z * rs * wb.z); ov[7] = (bf16)(b.w * rs * wb.w);
    *(bf16x8*)(out + row * H + base) = ov;
}

// ------- convert + transpose: W (K x N fp32) -> Wt (N*rmul+roff rows) -----
__global__ __launch_bounds__(256) void k_convT(const float* __restrict__ W,
        bf16* __restrict__ Wt, int K, int N, int rmul, int roff) {
    __shared__ float t[32][33];
    int k0 = blockIdx.x * 32, n0 = blockIdx.y * 32;
    int tx = threadIdx.x, ty = threadIdx.y;
#pragma unroll
    for (int i = 0; i < 4; i++)
        t[ty + i * 8][tx] = W[(size_t)(k0 + ty + i * 8) * N + n0 + tx];
    __syncthreads();
#pragma unroll
    for (int i = 0; i < 4; i++)
        Wt[((size_t)(n0 + ty + i * 8) * rmul + roff) * K + k0 + tx] =
            (bf16)t[tx][ty + i * 8];
}

// ------- bf16 transpose: in (R x C) -> out (C x R) ------------------------
__global__ __launch_bounds__(256) void k_transpose(const bf16* __restrict__ in,
        bf16* __restrict__ out, int R, int C) {
    __shared__ bf16 t[32][33];
    int r0 = blockIdx.x * 32, c0 = blockIdx.y * 32;
    int tx = threadIdx.x & 31, ty = threadIdx.x >> 5;
#pragma unroll
    for (int i = 0; i < 4; i++)
        t[ty + i * 8][tx] = in[(size_t)(r0 + ty + i * 8) * C + c0 + tx];
    __syncthreads();
#pragma unroll
    for (int i = 0; i < 4; i++)
        out[(size_t)(c0 + ty + i * 8) * R + r0 + tx] = t[tx][ty + i * 8];
}

// ---------------- GEMM v5: 8-phase, ONE barrier/phase, compiler waits -----
// BM=BN=256, BK=64, 2 K-tiles/iter, 8 waves (2M x 4N), per-wave 128x64.
// LDS 128KB: A buf0@0, A buf1@32K, B buf0@64K, B buf1@96K; half = 16KB,
// 128B rows XOR-swizzled byte^=((row&7)<<4); GLP dest linear, source
// pre-swizzled (rule 21).
// Per phase: {ds_reads (compiler-tracked lgkmcnt) || stage 1 half-tile ->
// setprio(1) MFMA setprio(0) -> s_barrier(+mem clobber)}. vmcnt(6) only at
// P4/P8 (never 0 mid-loop). No asm lgkmcnt, no sched_barrier: the compiler's
// fine-grained waits let read-completion hide under MFMA (m97 r109 lesson;
// m141: order-pinning regresses). Slab lifetime: every overwrite is >=1
// barrier after its last read (same schedule as v4, verified).
// EPI: 3 = fp32 partial (split-K), 4 = fused gate/up: even col=gate, odd=up,
//      write silu(g)*u to outp[row][col>>1] (bf16), even lanes store.
template<int EPI>
__global__ __launch_bounds__(512, 2) void k_gemm5(const bf16* __restrict__ A,
        const bf16* __restrict__ Bt, void* __restrict__ outp,
        const void* __restrict__ aux, int M, int N, int K, int ksplit) {
    extern __shared__ char lds[];
    const int tid = threadIdx.x, wave = tid >> 6, lane = tid & 63;
    const int lr = lane & 15, kg = lane >> 4;
    const int wm = wave >> 2, wn = wave & 3;
    const int bn = blockIdx.x, bm = blockIdx.y, split = blockIdx.z;
    const int row0 = bm * 256, col0 = bn * 256;
    const int kbeg = split * ksplit;
    const int NT = ksplit >> 6;          // K-tiles of 64
    const size_t K2 = (size_t)K * 2;
    const int xorm = (lr & 7) << 4;

    char* const A0p = lds;
    char* const A1p = lds + 32768;
    char* const B0p = lds + 65536;
    char* const B1p = lds + 98304;

    size_t soff[2];
#pragma unroll
    for (int s = 0; s < 2; s++) {
        int d = s * 8192 + tid * 16;
        int rh = d >> 7, c = d & 127;
        soff[s] = (size_t)rh * K2 + (c ^ ((rh & 7) << 4));
    }
    const char* Ab = (const char*)A + ((size_t)row0 * K + kbeg) * 2;
    const char* Bb = (const char*)Bt + ((size_t)col0 * K + kbeg) * 2;

    auto stA = [&](int t, int mh) {
        const char* src = Ab + (size_t)(mh * 128) * K2 + (size_t)t * 128;
        char* dst = lds + (t & 1) * 32768 + mh * 16384 + wave * 1024;
        GLP16(src + soff[0], dst);
        GLP16(src + soff[1], dst + 8192);
    };
    auto stB = [&](int t, int nh) {
        const char* src = Bb + (size_t)(nh * 128) * K2 + (size_t)t * 128;
        char* dst = lds + 65536 + (t & 1) * 32768 + nh * 16384 + wave * 1024;
        GLP16(src + soff[0], dst);
        GLP16(src + soff[1], dst + 8192);
    };

    f32x4 acc[8][4];
#pragma unroll
    for (int m = 0; m < 8; m++)
#pragma unroll
        for (int n = 0; n < 4; n++) acc[m][n] = (f32x4){0, 0, 0, 0};

    bf16x8 a[8], c0[4], c1[4];
    auto rdA = [&](const char* base, int mh) {
#pragma unroll
        for (int mi = 0; mi < 4; mi++)
#pragma unroll
            for (int kk = 0; kk < 2; kk++) {
                int rh = wm * 64 + mi * 16 + lr;
                int c = (kk * 64 + kg * 16) ^ xorm;
                a[mi * 2 + kk] = *(const bf16x8*)(base + mh * 16384 + rh * 128 + c);
            }
    };
    auto rdB = [&](const char* base, int nh, bf16x8 (&b)[4]) {
#pragma unroll
        for (int nj = 0; nj < 2; nj++)
#pragma unroll
            for (int kk = 0; kk < 2; kk++) {
                int rh = wn * 32 + nj * 16 + lr;
                int c = (kk * 64 + kg * 16) ^ xorm;
                b[nj * 2 + kk] = *(const bf16x8*)(base + nh * 16384 + rh * 128 + c);
            }
    };
    auto mm = [&](int mh, int nh, bf16x8 (&b)[4]) {
#pragma unroll
        for (int mi = 0; mi < 4; mi++)
#pragma unroll
            for (int nj = 0; nj < 2; nj++)
#pragma unroll
                for (int kk = 0; kk < 2; kk++)
                    acc[mh * 4 + mi][nh * 2 + nj] =
                        mfma16(a[mi * 2 + kk], b[nj * 2 + kk],
                               acc[mh * 4 + mi][nh * 2 + nj]);
    };

#define PBAR do { asm volatile("" ::: "memory"); \
                  __builtin_amdgcn_s_barrier(); \
                  asm volatile("" ::: "memory"); } while (0)

    // prologue: tile0 fully, tile1 all but A-h1; wait so tile0 is resident
    stA(0, 0); stB(0, 0); stB(0, 1); stA(0, 1);
    stA(1, 0); stB(1, 0); stB(1, 1);
    asm volatile("s_waitcnt vmcnt(6)" ::: "memory");
    PBAR;

    const int NIT = NT >> 1;
    for (int it = 0; it < NIT; ++it) {
        const int t = it * 2;
        const bool more = (t + 2 < NT);
        // P1 (0,0) buf0
        rdA(A0p, 0); rdB(B0p, 0, c0);
        stA(t + 1, 1);
        __builtin_amdgcn_s_setprio(1); mm(0, 0, c0); __builtin_amdgcn_s_setprio(0);
        PBAR;
        // P2 (0,1)
        rdB(B0p, 1, c1);
        if (more) stA(t + 2, 0);
        __builtin_amdgcn_s_setprio(1); mm(0, 1, c1); __builtin_amdgcn_s_setprio(0);
        PBAR;
        // P3 (1,1)
        rdA(A0p, 1);
        if (more) stB(t + 2, 0);
        __builtin_amdgcn_s_setprio(1); mm(1, 1, c1); __builtin_amdgcn_s_setprio(0);
        PBAR;
        // P4 (1,0)
        if (more) stB(t + 2, 1);
        __builtin_amdgcn_s_setprio(1); mm(1, 0, c0); __builtin_amdgcn_s_setprio(0);
        if (more) asm volatile("s_waitcnt vmcnt(6)" ::: "memory");
        else      asm volatile("s_waitcnt vmcnt(0)" ::: "memory");
        PBAR;
        // P5 (0,0) buf1
        rdA(A1p, 0); rdB(B1p, 0, c0);
        if (more) stA(t + 2, 1);
        __builtin_amdgcn_s_setprio(1); mm(0, 0, c0); __builtin_amdgcn_s_setprio(0);
        PBAR;
        // P6 (0,1)
        rdB(B1p, 1, c1);
        if (t + 3 < NT) stA(t + 3, 0);
        __builtin_amdgcn_s_setprio(1); mm(0, 1, c1); __builtin_amdgcn_s_setprio(0);
        PBAR;
        // P7 (1,1)
        rdA(A1p, 1);
        if (t + 3 < NT) stB(t + 3, 0);
        __builtin_amdgcn_s_setprio(1); mm(1, 1, c1); __builtin_amdgcn_s_setprio(0);
        PBAR;
        // P8 (1,0)
        if (t + 3 < NT) stB(t + 3, 1);
        __builtin_amdgcn_s_setprio(1); mm(1, 0, c0); __builtin_amdgcn_s_setprio(0);
        if (more) asm volatile("s_waitcnt vmcnt(6)" ::: "memory");
        PBAR;
    }
#undef PBAR

#pragma unroll
    for (int mi = 0; mi < 8; mi++)
#pragma unroll
        for (int ni = 0; ni < 4; ni++)
#pragma unroll
            for (int r = 0; r < 4; r++) {
                size_t row = row0 + (mi >> 2) * 128 + wm * 64 + (mi & 3) * 16 + kg * 4 + r;
                size_t col = col0 + (ni >> 1) * 128 + wn * 32 + (ni & 1) * 16 + lr;
                float vv = acc[mi][ni][r];
                if (EPI == 3) {
                    ((float*)outp)[(size_t)split * M * N + row * N + col] = vv;
                } else {  // EPI == 4: fused gate/up + silu
                    float pv = __shfl_xor(vv, 1);
                    float g = (lane & 1) ? pv : vv;
                    float u = (lane & 1) ? vv : pv;
                    float sg = g / (1.0f + __expf(-g));
                    if (!(lane & 1))
                        ((bf16*)outp)[row * (size_t)(N >> 1) + (col >> 1)] =
                            (bf16)(sg * u);
                }
            }
}

// ---- reduce: out = resid + sum_s parts[s], fp32, vectorized float4 -------
__global__ __launch_bounds__(256) void k_reduce(const float* __restrict__ parts,
        const float* __restrict__ resid, float* __restrict__ out,
        int ns, size_t n4) {
    size_t i = (size_t)blockIdx.x * 256 + threadIdx.x;
    if (i >= n4) return;
    float4 acc = ((const float4*)resid)[i];
    for (int s = 0; s < ns; s++) {
        float4 p = ((const float4*)(parts + (size_t)s * n4 * 4))[i];
        acc.x += p.x; acc.y += p.y; acc.z += p.z; acc.w += p.w;
    }
    ((float4*)out)[i] = acc;
}

// ---- fused: x2 = resid + sum parts; hb = rmsnorm(x2)*w  (row = 2048) -----
__global__ __launch_bounds__(256) void k_reduce_rms(const float* __restrict__ parts,
        const float* __restrict__ resid, const float* __restrict__ w,
        float* __restrict__ x2, bf16* __restrict__ hb, int ns) {
    const int H = 2048;
    size_t row = blockIdx.x;
    int base = threadIdx.x * 8;
    const float* rr = resid + row * H + base;
    float4 a = *(const float4*)rr;
    float4 b = *(const float4*)(rr + 4);
    for (int s = 0; s < ns; s++) {
        const float* pp = parts + (size_t)s * H * 2048 + row * H + base;
        float4 pa = *(const float4*)pp;
        float4 pb = *(const float4*)(pp + 4);
        a.x += pa.x; a.y += pa.y; a.z += pa.z; a.w += pa.w;
        b.x += pb.x; b.y += pb.y; b.z += pb.z; b.w += pb.w;
    }
    *(float4*)(x2 + row * H + base) = a;
    *(float4*)(x2 + row * H + base + 4) = b;
    float ss = a.x*a.x + a.y*a.y + a.z*a.z + a.w*a.w
             + b.x*b.x + b.y*b.y + b.z*b.z + b.w*b.w;
#pragma unroll
    for (int m = 32; m > 0; m >>= 1) ss += __shfl_xor(ss, m);
    __shared__ float red[4];
    if ((threadIdx.x & 63) == 0) red[threadIdx.x >> 6] = ss;
    __syncthreads();
    float tot = red[0] + red[1] + red[2] + red[3];
    float rs = rsqrtf(tot * (1.0f / H) + 1e-5f);
    float4 wa = *(const float4*)(w + base);
    float4 wb = *(const float4*)(w + base + 4);
    bf16x8 ov;
    ov[0] = (bf16)(a.x * rs * wa.x); ov[1] = (bf16)(a.y * rs * wa.y);
    ov[2] = (bf16)(a.z * rs * wa.z); ov[3] = (bf16)(a.w * rs * wa.w);
    ov[4] = (bf16)(b.x * rs * wb.x); ov[5] = (bf16)(b.y * rs * wb.y);
    ov[6] = (bf16)(b.z * rs * wb.z); ov[7] = (bf16)(b.w * rs * wb.w);
    *(bf16x8*)(hb + row * H + base) = ov;
}

// ---- QKV split-K reduce + scatter to qb/kb/vb ----------------------------
__global__ __launch_bounds__(256) void k_qkvfin(const float* __restrict__ parts,
        bf16* __restrict__ qb, bf16* __restrict__ kb, bf16* __restrict__ vb) {
    int s = blockIdx.x;
    int col = blockIdx.y * 1024 + threadIdx.x * 4;
    const float* p0 = parts + (size_t)s * 3072 + col;
    const float* p1 = p0 + (size_t)2048 * 3072;
    float4 a = *(const float4*)p0;
    float4 b = *(const float4*)p1;
    a.x += b.x; a.y += b.y; a.z += b.z; a.w += b.w;
    bf16x4 o;
    o[0] = (bf16)a.x; o[1] = (bf16)a.y; o[2] = (bf16)a.z; o[3] = (bf16)a.w;
    if (col < 2048)      *(bf16x4*)(qb + (size_t)s * 2048 + col) = o;
    else if (col < 2560) *(bf16x4*)(kb + (size_t)s * 512 + col - 2048) = o;
    else                 *(bf16x4*)(vb + (size_t)s * 512 + col - 2560) = o;
}

// ------------- RoPE + qk-norm, in-place on q (S x 2048) / k (S x 512) -----
__global__ __launch_bounds__(256) void k_rope(bf16* __restrict__ q,
        bf16* __restrict__ k) {
    int s = blockIdx.x, lane = threadIdx.x & 63;
    int hid = blockIdx.y * 4 + (threadIdx.x >> 6);
    bf16* p;
    if (hid < 16) p = q + (size_t)s * 2048 + hid * 128;
    else          p = k + (size_t)s * 512 + (hid - 16) * 128;
    float x1 = (float)p[lane], x2 = (float)p[lane + 64];
    float f = exp2f((float)lane * -0.2076205059304601f);  // 10000^(-lane/64)
    float sn, cs;
    sincosf((float)s * f, &sn, &cs);
    float o1 = x1 * cs - x2 * sn;
    float o2 = x2 * cs + x1 * sn;
    float ss = o1 * o1 + o2 * o2;
#pragma unroll
    for (int m = 32; m > 0; m >>= 1) ss += __shfl_xor(ss, m);
    float rs = rsqrtf(ss * (1.0f / 128.0f) + 1e-5f);
    p[lane] = (bf16)(o1 * rs);
    p[lane + 64] = (bf16)(o2 * rs);
}

// ------------- flash attention, GQA 16q/4kv, causal, tanh softcap ---------
__global__ __launch_bounds__(256) void k_attn(const bf16* __restrict__ qg,
        const bf16* __restrict__ kgl, const bf16* __restrict__ vtg,
        bf16* __restrict__ og) {
    extern __shared__ char alds[];
    int pi = blockIdx.x, h = blockIdx.y, kvh = h >> 2;
    int tid = threadIdx.x, wave = tid >> 6, lane = tid & 63;
    int lr = lane & 15, kgrp = lane >> 4;

    int rowQ[4], colQ[4], rowV[4], colV[4];
#pragma unroll
    for (int j = 0; j < 4; j++) {
        int p = j * 4096 + wave * 1024 + lane * 16;
        int ps = p ^ (((p >> 8) & 7) << 4);
        rowQ[j] = ps >> 8; colQ[j] = ps & 255;
        int pv = p ^ (((p >> 7) & 7) << 4);
        rowV[j] = pv >> 7; colV[j] = pv & 127;
    }

    const float C1 = 0.08838834764831845f / 50.0f;  // 1/(50*sqrt(128))
    const float L2E50 = 72.13475204444817f;         // 50*log2(e)

#pragma unroll 1
    for (int half = 0; half < 2; ++half) {
        int qt = half ? (31 - pi) : pi;
        int nt = qt + 1;

#pragma unroll
        for (int j = 0; j < 4; j++)
            GLP16((const char*)qg + (size_t)(qt * 64 + rowQ[j]) * 4096 + h * 256 + colQ[j],
                  alds + j * 4096 + wave * 1024);
        for (int t = 0; t < 2 && t < nt; t++) {
#pragma unroll
            for (int j = 0; j < 4; j++)
                GLP16((const char*)kgl + (size_t)(t * 64 + rowQ[j]) * 1024 + kvh * 256 + colQ[j],
                      alds + 16384 + t * 16384 + j * 4096 + wave * 1024);
#pragma unroll
            for (int j = 0; j < 4; j++)
                GLP16((const char*)vtg + (size_t)(kvh * 128 + rowV[j]) * 4096 + t * 128 + colV[j],
                      alds + 49152 + t * 16384 + j * 4096 + wave * 1024);
        }
        if (nt > 1) asm volatile("s_waitcnt vmcnt(8)" ::: "memory");
        else        asm volatile("s_waitcnt vmcnt(0)" ::: "memory");
        __builtin_amdgcn_s_barrier();

        bf16x8 qf[4];
#pragma unroll
        for (int c = 0; c < 4; c++) {
            int b = (wave * 16 + lr) * 256 + c * 64 + kgrp * 16;
            qf[c] = *(const bf16x8*)(alds + (b ^ (((b >> 8) & 7) << 4)));
        }
        f32x4 accO[8];
#pragma unroll
        for (int n = 0; n < 8; n++) accO[n] = (f32x4){0, 0, 0, 0};
        float lsum[4] = {0, 0, 0, 0};
        int qrow = qt * 64 + wave * 16 + kgrp * 4;

        for (int kt = 0; kt < nt; kt++) {
            int buf = kt & 1;
            const char* Kb = alds + 16384 + buf * 16384;
            const char* Vb = alds + 49152 + buf * 16384;
            char* Pb = alds + 81920;
#pragma unroll
            for (int j = 0; j < 4; j++) {
                f32x4 s = {0, 0, 0, 0};
#pragma unroll
                for (int c = 0; c < 4; c++) {
                    int b = (j * 16 + lr) * 256 + c * 64 + kgrp * 16;
                    bf16x8 kf = *(const bf16x8*)(Kb + (b ^ (((b >> 8) & 7) << 4)));
                    s = mfma16(qf[c], kf, s);
                }
                int key = kt * 64 + j * 16 + lr;
#pragma unroll
                for (int r = 0; r < 4; r++) {
                    float y = s[r] * C1;
                    float y2 = y * y;
                    float u = fmaf(y2, 0.13333333f, -0.33333333f);
                    u = fmaf(y2, u, 1.0f);
                    float t5 = y * u;                       // tanh(y)
                    float pe = fmaf(t5, L2E50, -L2E50);     // (50t-50)*log2e
                    float pv = (key <= qrow + r) ? exp2f(pe) : 0.0f;
                    lsum[r] += pv;
                    int wb = (wave * 16 + kgrp * 4 + r) * 128 + (j * 16 + lr) * 2;
                    *(bf16*)(Pb + (wb ^ (((wb >> 7) & 7) << 4))) = (bf16)pv;
                }
            }
            bf16x8 pf[2];
#pragma unroll
            for (int ks2 = 0; ks2 < 2; ks2++) {
                int b = (wave * 16 + lr) * 128 + ks2 * 64 + kgrp * 16;
                pf[ks2] = *(const bf16x8*)(Pb + (b ^ (((b >> 7) & 7) << 4)));
            }
#pragma unroll
            for (int n = 0; n < 8; n++)
#pragma unroll
                for (int ks2 = 0; ks2 < 2; ks2++) {
                    int b = (n * 16 + lr) * 128 + ks2 * 64 + kgrp * 16;
                    bf16x8 vf = *(const bf16x8*)(Vb + (b ^ (((b >> 7) & 7) << 4)));
                    accO[n] = mfma16(pf[ks2], vf, accO[n]);
                }
            __builtin_amdgcn_s_barrier();
            bool more = (kt + 2 < nt);
            if (more) {
                int t = kt + 2;
#pragma unroll
                for (int j = 0; j < 4; j++)
                    GLP16((const char*)kgl + (size_t)(t * 64 + rowQ[j]) * 1024 + kvh * 256 + colQ[j],
                          alds + 16384 + buf * 16384 + j * 4096 + wave * 1024);
#pragma unroll
                for (int j = 0; j < 4; j++)
                    GLP16((const char*)vtg + (size_t)(kvh * 128 + rowV[j]) * 4096 + t * 128 + colV[j],
                          alds + 49152 + buf * 16384 + j * 4096 + wave * 1024);
            }
            if (kt + 1 < nt) {
                if (more) asm volatile("s_waitcnt vmcnt(8)" ::: "memory");
                else      asm volatile("s_waitcnt vmcnt(0)" ::: "memory");
                __builtin_amdgcn_s_barrier();
            }
        }
#pragma unroll
        for (int r = 0; r < 4; r++) {
            float t = lsum[r];
            t += __shfl_xor(t, 1); t += __shfl_xor(t, 2);
            t += __shfl_xor(t, 4); t += __shfl_xor(t, 8);
            lsum[r] = t;
        }
#pragma unroll
        for (int n = 0; n < 8; n++)
#pragma unroll
            for (int r = 0; r < 4; r++) {
                size_t row = qt * 64 + wave * 16 + kgrp * 4 + r;
                og[row * 2048 + h * 128 + n * 16 + lr] = (bf16)(accO[n][r] / lsum[r]);
            }
    }
}

// --------------------------------------------------------------------------
extern "C" void kernel_launch(void* const* d_in, const int* in_sizes, int n_in,
                              void* d_out, int out_size, void* d_ws, size_t ws_size,
                              hipStream_t stream) {
    const float* x      = (const float*)d_in[0];
    const float* attn_w = (const float*)d_in[1];
    const float* mlp_w  = (const float*)d_in[2];
    const float* wq     = (const float*)d_in[3];
    const float* wk     = (const float*)d_in[4];
    const float* wv     = (const float*)d_in[5];
    const float* wo     = (const float*)d_in[6];
    const float* wgate  = (const float*)d_in[7];
    const float* wup    = (const float*)d_in[8];
    const float* wdown  = (const float*)d_in[9];
    float* out = (float*)d_out;
    char* ws = (char*)d_ws;

    const size_t MB = 1024 * 1024;
    // timeline-disjoint workspace map:
    bf16* Wqkv = (bf16*)(ws + 0);        // [0,12.6) step 2-3
    bf16* vt   = (bf16*)(ws + 0);        // [0,2)    step 4-6 (Wqkv dead)
    float* pO  = (float*)(ws + 0);       // [0,64)   O partials split4 (vt dead)
    bf16* Wgu  = (bf16*)(ws + 0);        // [0,64)   interleaved gate/up (pO dead)
    float* pD  = (float*)(ws + 0);       // [0,64)   down partials (Wgu dead)
    bf16* WoT  = (bf16*)(ws + 64 * MB);  // [64,72)  step 7
    bf16* WdT  = (bf16*)(ws + 64 * MB);  // [64,96)  step 10 (WoT dead)
    bf16* hb   = (bf16*)(ws + 96 * MB);  // 8MB
    bf16* qb   = (bf16*)(ws + 104 * MB); // 8MB
    bf16* kb   = (bf16*)(ws + 112 * MB); // 2MB
    bf16* vb   = (bf16*)(ws + 114 * MB); // 2MB
    bf16* ob   = (bf16*)(ws + 116 * MB); // 8MB
    float* x2  = (float*)(ws + 124 * MB);// 16MB
    bf16* gb   = (bf16*)(ws + 140 * MB); // 32MB silu(g)*u
    float* pQ  = (float*)(ws + 116 * MB);// QKV partials 50.3MB [116,167)

    const int LDS5 = 131072;
    hipFuncSetAttribute((const void*)&k_gemm5<3>,
        hipFuncAttributeMaxDynamicSharedMemorySize, LDS5);
    hipFuncSetAttribute((const void*)&k_gemm5<4>,
        hipFuncAttributeMaxDynamicSharedMemorySize, LDS5);
    const int LDSA = 90112;
    hipFuncSetAttribute((const void*)&k_attn,
        hipFuncAttributeMaxDynamicSharedMemorySize, LDSA);

    dim3 cb(32, 8);
    const size_t n4 = (size_t)2048 * 2048 / 4;

    // 1. attn RMSNorm
    k_rmsnorm<<<2048, 256, 0, stream>>>(x, attn_w, hb);
    // 2. convert QKV weights into one [3072][2048] bf16 Bt
    k_convT<<<dim3(64, 64), cb, 0, stream>>>(wq, Wqkv, 2048, 2048, 1, 0);
    k_convT<<<dim3(64, 16), cb, 0, stream>>>(wk, Wqkv + 4194304, 2048, 512, 1, 0);
    k_convT<<<dim3(64, 16), cb, 0, stream>>>(wv, Wqkv + 5242880, 2048, 512, 1, 0);
    // 3. fused QKV projection, split-K=2 -> fp32 partials; reduce+scatter
    k_gemm5<3><<<dim3(12, 8, 2), 512, LDS5, stream>>>(hb, Wqkv, pQ, nullptr,
                                                      2048, 3072, 2048, 1024);
    k_qkvfin<<<dim3(2048, 3), 256, 0, stream>>>(pQ, qb, kb, vb);
    // 4. V transpose (vb[2048][512] -> vt[512][2048]); Wqkv dead now
    k_transpose<<<dim3(64, 16), 256, 0, stream>>>(vb, vt, 2048, 512);
    // 5. RoPE + qk-norm (in place)
    k_rope<<<dim3(2048, 5), 256, 0, stream>>>(qb, kb);
    // 6. attention (balanced pairing)
    k_attn<<<dim3(16, 16), 256, LDSA, stream>>>(qb, kb, vt, ob);
    // 7. O projection, split-K=4 -> fp32 partials; fused reduce+rmsnorm
    k_convT<<<dim3(64, 64), cb, 0, stream>>>(wo, WoT, 2048, 2048, 1, 0);
    k_gemm5<3><<<dim3(8, 8, 4), 512, LDS5, stream>>>(ob, WoT, pO, nullptr,
                                                     2048, 2048, 2048, 512);
    k_reduce_rms<<<2048, 256, 0, stream>>>(pO, x, mlp_w, x2, hb, 4);
    // 8. convert gate (even rows) + up (odd rows) interleaved [16384][2048]
    k_convT<<<dim3(64, 256), cb, 0, stream>>>(wgate, Wgu, 2048, 8192, 2, 0);
    k_convT<<<dim3(64, 256), cb, 0, stream>>>(wup, Wgu, 2048, 8192, 2, 1);
    // 9. fused gate+up GEMM with in-register silu epilogue -> gb
    k_gemm5<4><<<dim3(64, 8, 1), 512, LDS5, stream>>>(hb, Wgu, gb, nullptr,
                                                      2048, 16384, 2048, 2048);
    // 10. down GEMM, split-K=4 -> partials; reduce + residual -> out
    k_convT<<<dim3(256, 64), cb, 0, stream>>>(wdown, WdT, 8192, 2048, 1, 0);
    k_gemm5<3><<<dim3(8, 8, 4), 512, LDS5, stream>>>(gb, WdT, pD, nullptr,
                                                     2048, 2048, 8192, 2048);
    k_reduce<<<4096, 256, 0, stream>>>(pD, x2, out, 4, n4);
}